// Round 2
// baseline (1119.044 us; speedup 1.0000x reference)
//
#include <hip/hip_runtime.h>
#include <hip/hip_bf16.h>
#include <math.h>

#define B_  8
#define N_  4096
#define C_  512
#define H_  8
#define HD_ 64
#define M_  (B_*N_)        // 32768
#define K_  C_             // 512
#define D3_ (3*C_)         // 1536
#define SCALE_ 0.125f      // HD^-0.5

// ---------------- fp32 tiled GEMM (NT: both operands K-contiguous) ----------
// BM=BN=128, BK=16, 256 threads, 8x8 micro-tile per thread.
#define BM 128
#define BN 128
#define BK 16
#define LSTR 132           // padded LDS leading dim (128+4) to spread banks

// GEMM1: qkv[m,d] = sum_k x[m,k] * w_qkv[d,k];  d<512 -> q (d_out),
// 512..1023 -> k buf, 1024..1535 -> v buf. Layout of all: [B,N,C].
__global__ __launch_bounds__(256, 2)
void k_gemm_qkv(const float* __restrict__ X, const float* __restrict__ W,
                float* __restrict__ outQ, float* __restrict__ outK,
                float* __restrict__ outV)
{
    __shared__ float As[BK][LSTR];
    __shared__ float Bs[BK][LSTR];
    const int m0 = blockIdx.x * BM;
    const int d0 = blockIdx.y * BN;
    const int t  = threadIdx.x;
    const int tx = t & 15;          // output col group
    const int ty = t >> 4;          // output row group
    const int row = t >> 2;         // staging row 0..63
    const int c4  = (t & 3) * 4;    // staging k-offset 0/4/8/12

    const float* Arow0 = X + (size_t)(m0 + row)      * K_ + c4;
    const float* Arow1 = X + (size_t)(m0 + row + 64) * K_ + c4;
    const float* Wrow0 = W + (size_t)(d0 + row)      * K_ + c4;
    const float* Wrow1 = W + (size_t)(d0 + row + 64) * K_ + c4;

    float acc[8][8];
    #pragma unroll
    for (int i = 0; i < 8; ++i)
        #pragma unroll
        for (int j = 0; j < 8; ++j) acc[i][j] = 0.f;

    for (int k0 = 0; k0 < K_; k0 += BK) {
        float4 a0 = *(const float4*)(Arow0 + k0);
        float4 a1 = *(const float4*)(Arow1 + k0);
        float4 b0 = *(const float4*)(Wrow0 + k0);
        float4 b1 = *(const float4*)(Wrow1 + k0);
        __syncthreads();   // previous iter's reads done before overwrite
        As[c4+0][row]    = a0.x; As[c4+1][row]    = a0.y;
        As[c4+2][row]    = a0.z; As[c4+3][row]    = a0.w;
        As[c4+0][row+64] = a1.x; As[c4+1][row+64] = a1.y;
        As[c4+2][row+64] = a1.z; As[c4+3][row+64] = a1.w;
        Bs[c4+0][row]    = b0.x; Bs[c4+1][row]    = b0.y;
        Bs[c4+2][row]    = b0.z; Bs[c4+3][row]    = b0.w;
        Bs[c4+0][row+64] = b1.x; Bs[c4+1][row+64] = b1.y;
        Bs[c4+2][row+64] = b1.z; Bs[c4+3][row+64] = b1.w;
        __syncthreads();
        #pragma unroll
        for (int kk = 0; kk < BK; ++kk) {
            float4 av0 = *(const float4*)&As[kk][ty*8];
            float4 av1 = *(const float4*)&As[kk][ty*8+4];
            float4 bv0 = *(const float4*)&Bs[kk][tx*8];
            float4 bv1 = *(const float4*)&Bs[kk][tx*8+4];
            float a[8]  = {av0.x,av0.y,av0.z,av0.w,av1.x,av1.y,av1.z,av1.w};
            float bb[8] = {bv0.x,bv0.y,bv0.z,bv0.w,bv1.x,bv1.y,bv1.z,bv1.w};
            #pragma unroll
            for (int i = 0; i < 8; ++i)
                #pragma unroll
                for (int j = 0; j < 8; ++j)
                    acc[i][j] = fmaf(a[i], bb[j], acc[i][j]);
        }
    }

    float* dst; int dd;
    if (d0 < C_)        { dst = outQ; dd = d0; }
    else if (d0 < 2*C_) { dst = outK; dd = d0 - C_; }
    else                { dst = outV; dd = d0 - 2*C_; }
    const int dcol = dd + tx*8;
    #pragma unroll
    for (int i = 0; i < 8; ++i) {
        size_t off = (size_t)(m0 + ty*8 + i) * C_ + dcol;
        *(float4*)(dst + off)     = make_float4(acc[i][0],acc[i][1],acc[i][2],acc[i][3]);
        *(float4*)(dst + off + 4) = make_float4(acc[i][4],acc[i][5],acc[i][6],acc[i][7]);
    }
}

// GEMM2: out[m,d] = sum_k v[m,k]*gk[b,k]*w_proj[d,k] + b_proj[d] + q[m,d]
// q residual lives in `out` already; read-modify-write in place.
__global__ __launch_bounds__(256, 2)
void k_gemm_out(const float* __restrict__ V, const float* __restrict__ Wp,
                const float* __restrict__ gkf, const float* __restrict__ bproj,
                float* __restrict__ out)
{
    __shared__ float As[BK][LSTR];
    __shared__ float Bs[BK][LSTR];
    __shared__ float gks[C_];
    const int m0 = blockIdx.x * BM;
    const int d0 = blockIdx.y * BN;
    const int b  = m0 >> 12;        // 4096 rows per batch, BM|4096
    const int t  = threadIdx.x;
    const int tx = t & 15;
    const int ty = t >> 4;
    const int row = t >> 2;
    const int c4  = (t & 3) * 4;

    gks[t]       = gkf[b*C_ + t];
    gks[t + 256] = gkf[b*C_ + t + 256];

    const float* Arow0 = V  + (size_t)(m0 + row)      * K_ + c4;
    const float* Arow1 = V  + (size_t)(m0 + row + 64) * K_ + c4;
    const float* Wrow0 = Wp + (size_t)(d0 + row)      * K_ + c4;
    const float* Wrow1 = Wp + (size_t)(d0 + row + 64) * K_ + c4;

    float acc[8][8];
    #pragma unroll
    for (int i = 0; i < 8; ++i)
        #pragma unroll
        for (int j = 0; j < 8; ++j) acc[i][j] = 0.f;

    for (int k0 = 0; k0 < K_; k0 += BK) {
        float4 a0 = *(const float4*)(Arow0 + k0);
        float4 a1 = *(const float4*)(Arow1 + k0);
        float4 b0 = *(const float4*)(Wrow0 + k0);
        float4 b1 = *(const float4*)(Wrow1 + k0);
        __syncthreads();            // also covers initial gks writes
        float g0 = gks[k0+c4+0], g1 = gks[k0+c4+1];
        float g2 = gks[k0+c4+2], g3 = gks[k0+c4+3];
        As[c4+0][row]    = a0.x*g0; As[c4+1][row]    = a0.y*g1;
        As[c4+2][row]    = a0.z*g2; As[c4+3][row]    = a0.w*g3;
        As[c4+0][row+64] = a1.x*g0; As[c4+1][row+64] = a1.y*g1;
        As[c4+2][row+64] = a1.z*g2; As[c4+3][row+64] = a1.w*g3;
        Bs[c4+0][row]    = b0.x; Bs[c4+1][row]    = b0.y;
        Bs[c4+2][row]    = b0.z; Bs[c4+3][row]    = b0.w;
        Bs[c4+0][row+64] = b1.x; Bs[c4+1][row+64] = b1.y;
        Bs[c4+2][row+64] = b1.z; Bs[c4+3][row+64] = b1.w;
        __syncthreads();
        #pragma unroll
        for (int kk = 0; kk < BK; ++kk) {
            float4 av0 = *(const float4*)&As[kk][ty*8];
            float4 av1 = *(const float4*)&As[kk][ty*8+4];
            float4 bv0 = *(const float4*)&Bs[kk][tx*8];
            float4 bv1 = *(const float4*)&Bs[kk][tx*8+4];
            float a[8]  = {av0.x,av0.y,av0.z,av0.w,av1.x,av1.y,av1.z,av1.w};
            float bb[8] = {bv0.x,bv0.y,bv0.z,bv0.w,bv1.x,bv1.y,bv1.z,bv1.w};
            #pragma unroll
            for (int i = 0; i < 8; ++i)
                #pragma unroll
                for (int j = 0; j < 8; ++j)
                    acc[i][j] = fmaf(a[i], bb[j], acc[i][j]);
        }
    }

    const int dcol = d0 + tx*8;
    float bp[8];
    #pragma unroll
    for (int j = 0; j < 8; ++j) bp[j] = bproj[dcol + j];
    #pragma unroll
    for (int i = 0; i < 8; ++i) {
        size_t off = (size_t)(m0 + ty*8 + i) * C_ + dcol;
        float4 q0 = *(const float4*)(out + off);
        float4 q1 = *(const float4*)(out + off + 4);
        *(float4*)(out + off) = make_float4(acc[i][0]+bp[0]+q0.x,
                                            acc[i][1]+bp[1]+q0.y,
                                            acc[i][2]+bp[2]+q0.z,
                                            acc[i][3]+bp[3]+q0.w);
        *(float4*)(out + off + 4) = make_float4(acc[i][4]+bp[4]+q1.x,
                                                acc[i][5]+bp[5]+q1.y,
                                                acc[i][6]+bp[6]+q1.z,
                                                acc[i][7]+bp[7]+q1.w);
    }
}

// Pooling: one block per (b,h). scores s[n] = dot(src[b,n,h,:], w)*SCALE,
// softmax over n, gout[bh,:] = sum_n softmax(s)[n] * src[b,n,h,:].
// For beta pass, w[c] = w_k[h,c]*global_q[bh,c] (gq_in non-null).
__global__ __launch_bounds__(1024)
void k_pool(const float* __restrict__ src, const float* __restrict__ wvec,
            const float* __restrict__ gq_in, float* __restrict__ gout)
{
    __shared__ float sl[N_];      // scores -> exp values -> reduce scratch
    __shared__ float red[16];
    __shared__ float stat[2];
    const int bh = blockIdx.x;
    const int b = bh >> 3, h = bh & 7;
    const int t = threadIdx.x;
    const int lane = t & 63, wv = t >> 6;    // 16 waves

    float w = wvec[h*HD_ + lane];
    if (gq_in) w *= gq_in[bh*HD_ + lane];
    const float* base = src + (size_t)b*N_*C_ + h*HD_;

    // pass 1: scores (wave-per-row dot, 4-way unrolled for MLP)
    for (int n0 = wv*4; n0 < N_; n0 += 64) {
        float x0 = base[(size_t)(n0+0)*C_ + lane] * w;
        float x1 = base[(size_t)(n0+1)*C_ + lane] * w;
        float x2 = base[(size_t)(n0+2)*C_ + lane] * w;
        float x3 = base[(size_t)(n0+3)*C_ + lane] * w;
        #pragma unroll
        for (int off = 32; off; off >>= 1) {
            x0 += __shfl_xor(x0, off);
            x1 += __shfl_xor(x1, off);
            x2 += __shfl_xor(x2, off);
            x3 += __shfl_xor(x3, off);
        }
        if (lane == 0) {
            sl[n0+0] = x0*SCALE_; sl[n0+1] = x1*SCALE_;
            sl[n0+2] = x2*SCALE_; sl[n0+3] = x3*SCALE_;
        }
    }
    __syncthreads();

    // max
    float m = -1e30f;
    for (int n = t; n < N_; n += 1024) m = fmaxf(m, sl[n]);
    #pragma unroll
    for (int off = 32; off; off >>= 1) m = fmaxf(m, __shfl_xor(m, off));
    if (lane == 0) red[wv] = m;
    __syncthreads();
    if (t == 0) {
        float mm = red[0];
        for (int i = 1; i < 16; ++i) mm = fmaxf(mm, red[i]);
        stat[0] = mm;
    }
    __syncthreads();
    m = stat[0];

    // exp + sum
    float s = 0.f;
    for (int n = t; n < N_; n += 1024) {
        float e = expf(sl[n] - m);
        sl[n] = e;
        s += e;
    }
    #pragma unroll
    for (int off = 32; off; off >>= 1) s += __shfl_xor(s, off);
    if (lane == 0) red[wv] = s;
    __syncthreads();
    if (t == 0) {
        float ss = 0.f;
        for (int i = 0; i < 16; ++i) ss += red[i];
        stat[1] = 1.0f / ss;
    }
    __syncthreads();
    const float inv = stat[1];

    // pass 2: weighted sum over n, lane owns channel c=lane
    float acc = 0.f;
    for (int n0 = wv*4; n0 < N_; n0 += 64) {
        acc = fmaf(sl[n0+0], base[(size_t)(n0+0)*C_ + lane], acc);
        acc = fmaf(sl[n0+1], base[(size_t)(n0+1)*C_ + lane], acc);
        acc = fmaf(sl[n0+2], base[(size_t)(n0+2)*C_ + lane], acc);
        acc = fmaf(sl[n0+3], base[(size_t)(n0+3)*C_ + lane], acc);
    }
    __syncthreads();                 // everyone done reading sl
    sl[wv*64 + lane] = acc;          // reuse first 1024 slots
    __syncthreads();
    if (t < 64) {
        float g = 0.f;
        #pragma unroll
        for (int i = 0; i < 16; ++i) g += sl[i*64 + t];
        gout[bh*HD_ + t] = g * inv;
    }
}

extern "C" void kernel_launch(void* const* d_in, const int* in_sizes, int n_in,
                              void* d_out, int out_size, void* d_ws, size_t ws_size,
                              hipStream_t stream)
{
    (void)in_sizes; (void)n_in; (void)out_size; (void)ws_size;
    const float* x      = (const float*)d_in[0];
    const float* w_qkv  = (const float*)d_in[1];
    const float* w_proj = (const float*)d_in[2];
    const float* b_proj = (const float*)d_in[3];
    const float* w_q    = (const float*)d_in[4];
    const float* w_k    = (const float*)d_in[5];
    float* out = (float*)d_out;     // q_flat staged here, then final out

    float* kbuf = (float*)d_ws;                  // [B,N,C] 64 MB
    float* vbuf = kbuf + (size_t)M_ * C_;        // [B,N,C] 64 MB
    float* gq   = vbuf + (size_t)M_ * C_;        // [B*H, HD]
    float* gkf  = gq + B_*H_*HD_;                // [B, C] (== [B*H, HD] flat)

    dim3 g1(M_/BM, D3_/BN);
    k_gemm_qkv<<<g1, 256, 0, stream>>>(x, w_qkv, out, kbuf, vbuf);

    k_pool<<<B_*H_, 1024, 0, stream>>>(out, w_q, nullptr, gq);
    k_pool<<<B_*H_, 1024, 0, stream>>>(kbuf, w_k, gq, gkf);

    dim3 g2(M_/BM, C_/BN);
    k_gemm_out<<<g2, 256, 0, stream>>>(vbuf, w_proj, gkf, b_proj, out);
}

// Round 3
// 308.623 us; speedup vs baseline: 3.6259x; 3.6259x over previous
//
#include <hip/hip_runtime.h>
#include <hip/hip_bf16.h>
#include <math.h>

#define B_  8
#define N_  4096
#define C_  512
#define H_  8
#define HD_ 64
#define M_  (B_*N_)        // 32768
#define K_  C_             // 512
#define D3_ (3*C_)         // 1536
#define SCALE_ 0.125f
#define CH_ 8              // pool chunks per (b,h)
#define CHN (N_/CH_)       // 512 rows per chunk

using f32x4  = __attribute__((ext_vector_type(4))) float;
using bf16x8 = __attribute__((ext_vector_type(8))) short;

__device__ __forceinline__ unsigned short f2bf(float f) {
    unsigned int u = __builtin_bit_cast(unsigned int, f);
    u += 0x7FFFu + ((u >> 16) & 1u);   // RNE
    return (unsigned short)(u >> 16);
}
__device__ __forceinline__ float bf2f(unsigned short s) {
    unsigned int u = ((unsigned int)s) << 16;
    return __builtin_bit_cast(float, u);
}

// async global->LDS, 16B per lane; LDS dest is wave-uniform base (+lane*16 by HW)
__device__ __forceinline__ void gl_lds16(const void* g, void* l) {
    __builtin_amdgcn_global_load_lds(
        (const __attribute__((address_space(1))) unsigned int*)(g),
        (__attribute__((address_space(3))) unsigned int*)(l), 16, 0, 0);
}

// ---------------------------------------------------------------------------
// bf16 MFMA GEMM, m97 structure: 128x128 tile, BK=32, 256 thr (4 waves),
// wave w -> 64x64 subtile (wr=w>>1, wc=w&1), acc 4x4 of 16x16 frags.
// LDS tile [128 rows][4 slots of 16B]; slot holds k-chunk (slot ^ ((row>>1)&3))
// via pre-swizzled global source; readers apply same XOR.
// A[m,k], B[d,k] both K-contiguous (NT).
// ---------------------------------------------------------------------------
__global__ __launch_bounds__(256, 2)
void k_gemm1(const unsigned short* __restrict__ Ag, const unsigned short* __restrict__ Bg,
             float* __restrict__ outQ, unsigned short* __restrict__ outK,
             unsigned short* __restrict__ outV)
{
    __shared__ __align__(16) unsigned char lds[16384];   // A 8KB | B 8KB
    const int m0 = blockIdx.x * 128;
    const int d0 = blockIdx.y * 128;
    const int t = threadIdx.x, lane = t & 63, w = t >> 6;
    const int wr = w >> 1, wc = w & 1;
    const int lrow = lane >> 2, lslot = lane & 3;
    const int fr = lane & 15, g = lane >> 4;

    f32x4 acc[4][4];
    #pragma unroll
    for (int i = 0; i < 4; ++i)
        #pragma unroll
        for (int j = 0; j < 4; ++j) acc[i][j] = (f32x4){0.f,0.f,0.f,0.f};

    for (int k0 = 0; k0 < K_; k0 += 32) {
        #pragma unroll
        for (int s = 0; s < 2; ++s) {
            const int seg = w*2 + s;
            const int row = seg*16 + lrow;
            const int ch  = lslot ^ ((row >> 1) & 3);
            gl_lds16(Ag + (size_t)(m0+row)*K_ + k0 + ch*8, lds + seg*1024);
            gl_lds16(Bg + (size_t)(d0+row)*K_ + k0 + ch*8, lds + 8192 + seg*1024);
        }
        __syncthreads();   // compiler drains vmcnt(0) before barrier
        bf16x8 aF[4], bF[4];
        #pragma unroll
        for (int i = 0; i < 4; ++i) {
            const int r = wr*64 + i*16 + fr;
            const int sl = g ^ ((r >> 1) & 3);
            aF[i] = *(const bf16x8*)(lds + r*64 + sl*16);
        }
        #pragma unroll
        for (int j = 0; j < 4; ++j) {
            const int r = wc*64 + j*16 + fr;
            const int sl = g ^ ((r >> 1) & 3);
            bF[j] = *(const bf16x8*)(lds + 8192 + r*64 + sl*16);
        }
        #pragma unroll
        for (int i = 0; i < 4; ++i)
            #pragma unroll
            for (int j = 0; j < 4; ++j)
                acc[i][j] = __builtin_amdgcn_mfma_f32_16x16x32_bf16(aF[i], bF[j], acc[i][j], 0, 0, 0);
        __syncthreads();
    }

    // epilogue: C/D layout col=lane&15, row=(lane>>4)*4+reg (m89-verified)
    #pragma unroll
    for (int i = 0; i < 4; ++i)
        #pragma unroll
        for (int j = 0; j < 4; ++j) {
            const int trow = wr*64 + i*16 + (lane >> 4)*4;
            const int tcol = wc*64 + j*16 + (lane & 15);
            const int d = d0 + tcol;
            #pragma unroll
            for (int p = 0; p < 4; ++p) {
                const size_t m = (size_t)(m0 + trow + p);
                const float vv = acc[i][j][p];
                if (d0 < C_)          outQ[m*C_ + d] = vv;
                else if (d0 < 2*C_)   outK[m*C_ + (d - C_)] = f2bf(vv);
                else                  outV[m*C_ + (d - 2*C_)] = f2bf(vv);
            }
        }
}

// GEMM2: out[m,d] = sum_k v_bf16[m,k]*wpb[b][d,k] + bproj[d] + q(out)[m,d]
__global__ __launch_bounds__(256, 2)
void k_gemm2(const unsigned short* __restrict__ Ag, const unsigned short* __restrict__ Wpb,
             const float* __restrict__ bproj, float* __restrict__ out)
{
    __shared__ __align__(16) unsigned char lds[16384];
    const int m0 = blockIdx.x * 128;
    const int d0 = blockIdx.y * 128;
    const int b  = m0 >> 12;
    const unsigned short* Bg = Wpb + (size_t)b * C_ * C_;
    const int t = threadIdx.x, lane = t & 63, w = t >> 6;
    const int wr = w >> 1, wc = w & 1;
    const int lrow = lane >> 2, lslot = lane & 3;
    const int fr = lane & 15, g = lane >> 4;

    f32x4 acc[4][4];
    #pragma unroll
    for (int i = 0; i < 4; ++i)
        #pragma unroll
        for (int j = 0; j < 4; ++j) acc[i][j] = (f32x4){0.f,0.f,0.f,0.f};

    for (int k0 = 0; k0 < K_; k0 += 32) {
        #pragma unroll
        for (int s = 0; s < 2; ++s) {
            const int seg = w*2 + s;
            const int row = seg*16 + lrow;
            const int ch  = lslot ^ ((row >> 1) & 3);
            gl_lds16(Ag + (size_t)(m0+row)*K_ + k0 + ch*8, lds + seg*1024);
            gl_lds16(Bg + (size_t)(d0+row)*K_ + k0 + ch*8, lds + 8192 + seg*1024);
        }
        __syncthreads();
        bf16x8 aF[4], bF[4];
        #pragma unroll
        for (int i = 0; i < 4; ++i) {
            const int r = wr*64 + i*16 + fr;
            const int sl = g ^ ((r >> 1) & 3);
            aF[i] = *(const bf16x8*)(lds + r*64 + sl*16);
        }
        #pragma unroll
        for (int j = 0; j < 4; ++j) {
            const int r = wc*64 + j*16 + fr;
            const int sl = g ^ ((r >> 1) & 3);
            bF[j] = *(const bf16x8*)(lds + 8192 + r*64 + sl*16);
        }
        #pragma unroll
        for (int i = 0; i < 4; ++i)
            #pragma unroll
            for (int j = 0; j < 4; ++j)
                acc[i][j] = __builtin_amdgcn_mfma_f32_16x16x32_bf16(aF[i], bF[j], acc[i][j], 0, 0, 0);
        __syncthreads();
    }

    #pragma unroll
    for (int i = 0; i < 4; ++i)
        #pragma unroll
        for (int j = 0; j < 4; ++j) {
            const int trow = wr*64 + i*16 + (lane >> 4)*4;
            const int tcol = wc*64 + j*16 + (lane & 15);
            const int d = d0 + tcol;
            const float bp = bproj[d];
            #pragma unroll
            for (int p = 0; p < 4; ++p) {
                const size_t off = (size_t)(m0 + trow + p)*C_ + d;
                out[off] = acc[i][j][p] + bp + out[off];   // q residual in-place
            }
        }
}

// ---------------------------------------------------------------------------
// chunked pooling (flash-style partials): grid = 64*CH_ blocks, 256 thr.
// chunk computes local max m, raw expsum s, raw weighted vec pv (64 ch).
// ---------------------------------------------------------------------------
template<int SRCBF>
__device__ __forceinline__ float loadsrc(const void* s, size_t idx) {
    if constexpr (SRCBF) return bf2f(((const unsigned short*)s)[idx]);
    else                 return ((const float*)s)[idx];
}

template<int SRCBF>
__global__ __launch_bounds__(256)
void k_pool_part(const void* __restrict__ srcv, const float* __restrict__ wvec,
                 const float* __restrict__ gq_in,
                 float* __restrict__ pm, float* __restrict__ ps, float* __restrict__ pv)
{
    __shared__ float sl[CHN];
    __shared__ float red[4];
    __shared__ float stat[2];
    __shared__ float wsum[4][64];
    const int bid = blockIdx.x;
    const int bh = bid >> 3, ch = bid & 7;
    const int b = bh >> 3, h = bh & 7;
    const int t = threadIdx.x, lane = t & 63, wv = t >> 6;

    float w = wvec[h*HD_ + lane];
    if (gq_in) w *= gq_in[bh*HD_ + lane];
    const size_t rowbase = ((size_t)b*N_ + (size_t)ch*CHN)*C_ + h*HD_ + lane;

    for (int n0 = wv*4; n0 < CHN; n0 += 16) {
        float x0 = loadsrc<SRCBF>(srcv, rowbase + (size_t)(n0+0)*C_) * w;
        float x1 = loadsrc<SRCBF>(srcv, rowbase + (size_t)(n0+1)*C_) * w;
        float x2 = loadsrc<SRCBF>(srcv, rowbase + (size_t)(n0+2)*C_) * w;
        float x3 = loadsrc<SRCBF>(srcv, rowbase + (size_t)(n0+3)*C_) * w;
        #pragma unroll
        for (int off = 32; off; off >>= 1) {
            x0 += __shfl_xor(x0, off); x1 += __shfl_xor(x1, off);
            x2 += __shfl_xor(x2, off); x3 += __shfl_xor(x3, off);
        }
        if (lane == 0) {
            sl[n0+0] = x0*SCALE_; sl[n0+1] = x1*SCALE_;
            sl[n0+2] = x2*SCALE_; sl[n0+3] = x3*SCALE_;
        }
    }
    __syncthreads();

    float m = fmaxf(sl[t], sl[t+256]);
    #pragma unroll
    for (int off = 32; off; off >>= 1) m = fmaxf(m, __shfl_xor(m, off));
    if (lane == 0) red[wv] = m;
    __syncthreads();
    if (t == 0) stat[0] = fmaxf(fmaxf(red[0], red[1]), fmaxf(red[2], red[3]));
    __syncthreads();
    m = stat[0];

    float e0 = __expf(sl[t] - m), e1 = __expf(sl[t+256] - m);
    sl[t] = e0; sl[t+256] = e1;
    float s = e0 + e1;
    #pragma unroll
    for (int off = 32; off; off >>= 1) s += __shfl_xor(s, off);
    if (lane == 0) red[wv] = s;
    __syncthreads();
    if (t == 0) stat[1] = red[0] + red[1] + red[2] + red[3];
    __syncthreads();

    float acc = 0.f;
    for (int n0 = wv*4; n0 < CHN; n0 += 16) {
        acc = fmaf(sl[n0+0], loadsrc<SRCBF>(srcv, rowbase + (size_t)(n0+0)*C_), acc);
        acc = fmaf(sl[n0+1], loadsrc<SRCBF>(srcv, rowbase + (size_t)(n0+1)*C_), acc);
        acc = fmaf(sl[n0+2], loadsrc<SRCBF>(srcv, rowbase + (size_t)(n0+2)*C_), acc);
        acc = fmaf(sl[n0+3], loadsrc<SRCBF>(srcv, rowbase + (size_t)(n0+3)*C_), acc);
    }
    wsum[wv][lane] = acc;
    __syncthreads();
    if (t < 64) {
        pv[(size_t)bid*HD_ + t] = wsum[0][t] + wsum[1][t] + wsum[2][t] + wsum[3][t];
        if (t == 0) { pm[bid] = stat[0]; ps[bid] = stat[1]; }
    }
}

__global__ __launch_bounds__(64)
void k_pool_comb(const float* __restrict__ pm, const float* __restrict__ ps,
                 const float* __restrict__ pv, float* __restrict__ gout)
{
    const int bh = blockIdx.x, c = threadIdx.x;
    float m = -1e30f;
    #pragma unroll
    for (int ch = 0; ch < CH_; ++ch) m = fmaxf(m, pm[bh*CH_ + ch]);
    float s = 0.f, g = 0.f;
    #pragma unroll
    for (int ch = 0; ch < CH_; ++ch) {
        const float e = __expf(pm[bh*CH_ + ch] - m);
        s += ps[bh*CH_ + ch] * e;
        g += pv[(size_t)(bh*CH_ + ch)*HD_ + c] * e;
    }
    gout[bh*HD_ + c] = g / s;
}

// fp32 -> bf16 bulk convert (float4 in, ushort4 out)
__global__ void k_cvt(const float* __restrict__ in, unsigned short* __restrict__ o, int n4)
{
    int i = blockIdx.x*blockDim.x + threadIdx.x;
    const int stride = gridDim.x*blockDim.x;
    for (; i < n4; i += stride) {
        const float4 f = ((const float4*)in)[i];
        ushort4 r; r.x = f2bf(f.x); r.y = f2bf(f.y); r.z = f2bf(f.z); r.w = f2bf(f.w);
        ((ushort4*)o)[i] = r;
    }
}

// wpb[b][d][k] = bf16(w_proj[d][k] * gkf[b*512 + k])
__global__ void k_fold(const float* __restrict__ wp, const float* __restrict__ gkf,
                       unsigned short* __restrict__ wpb)
{
    const int i = blockIdx.x*256 + threadIdx.x;     // quad index over [8][512][512]
    const int idx4 = i*4;
    const int b  = idx4 >> 18;
    const int wi = idx4 & 262143;
    const int k  = idx4 & 511;
    const float4 wv4 = *(const float4*)(wp + wi);
    const float* gk = gkf + b*C_ + k;
    ushort4 r;
    r.x = f2bf(wv4.x * gk[0]); r.y = f2bf(wv4.y * gk[1]);
    r.z = f2bf(wv4.z * gk[2]); r.w = f2bf(wv4.w * gk[3]);
    ((ushort4*)wpb)[i] = r;
}

extern "C" void kernel_launch(void* const* d_in, const int* in_sizes, int n_in,
                              void* d_out, int out_size, void* d_ws, size_t ws_size,
                              hipStream_t stream)
{
    (void)in_sizes; (void)n_in; (void)out_size; (void)ws_size;
    const float* x      = (const float*)d_in[0];
    const float* w_qkv  = (const float*)d_in[1];
    const float* w_proj = (const float*)d_in[2];
    const float* b_proj = (const float*)d_in[3];
    const float* w_q    = (const float*)d_in[4];
    const float* w_k    = (const float*)d_in[5];
    float* out = (float*)d_out;

    unsigned short* xb  = (unsigned short*)d_ws;           // [M,K] bf16   32MB
    unsigned short* wqb = xb  + (size_t)M_*K_;             // [D3,K] bf16  1.5MB
    unsigned short* kb  = wqb + (size_t)D3_*K_;            // [M,C] bf16   32MB
    unsigned short* vb  = kb  + (size_t)M_*C_;             // [M,C] bf16   32MB
    unsigned short* wpb = vb  + (size_t)M_*C_;             // [8,C,C] bf16 4MB
    float* gq  = (float*)(wpb + (size_t)8*C_*C_);          // [64,64]
    float* gkf = gq  + B_*H_*HD_;                          // [64,64]
    float* pm  = gkf + B_*H_*HD_;                          // [512]
    float* ps  = pm + 64*CH_;
    float* pv  = ps + 64*CH_;                              // [512,64]

    k_cvt<<<2048, 256, 0, stream>>>(x, xb, M_*K_/4);
    k_cvt<<<768,  256, 0, stream>>>(w_qkv, wqb, D3_*K_/4);

    dim3 g1(M_/128, D3_/128);
    k_gemm1<<<g1, 256, 0, stream>>>(xb, wqb, out, kb, vb);

    k_pool_part<0><<<64*CH_, 256, 0, stream>>>(out, w_q, nullptr, pm, ps, pv);
    k_pool_comb<<<64, 64, 0, stream>>>(pm, ps, pv, gq);
    k_pool_part<1><<<64*CH_, 256, 0, stream>>>(kb, w_k, gq, pm, ps, pv);
    k_pool_comb<<<64, 64, 0, stream>>>(pm, ps, pv, gkf);

    k_fold<<<2048, 256, 0, stream>>>(w_proj, gkf, wpb);

    dim3 g2(M_/128, C_/128);
    k_gemm2<<<g2, 256, 0, stream>>>(vb, wpb, b_proj, out);
}

// Round 4
// 271.043 us; speedup vs baseline: 4.1287x; 1.1387x over previous
//
#include <hip/hip_runtime.h>
#include <hip/hip_bf16.h>
#include <math.h>

#define B_  8
#define N_  4096
#define C_  512
#define H_  8
#define HD_ 64
#define M_  (B_*N_)        // 32768
#define K_  C_             // 512
#define D3_ (3*C_)         // 1536
#define SCALE_ 0.125f

using f32x4  = __attribute__((ext_vector_type(4))) float;
using bf16x8 = __attribute__((ext_vector_type(8))) short;

__device__ __forceinline__ unsigned short f2bf(float f) {
    unsigned int u = __builtin_bit_cast(unsigned int, f);
    u += 0x7FFFu + ((u >> 16) & 1u);   // RNE
    return (unsigned short)(u >> 16);
}
__device__ __forceinline__ float bf2f(unsigned short s) {
    unsigned int u = ((unsigned int)s) << 16;
    return __builtin_bit_cast(float, u);
}

__device__ __forceinline__ void gl_lds16(const void* g, void* l) {
    __builtin_amdgcn_global_load_lds(
        (const __attribute__((address_space(1))) unsigned int*)(g),
        (__attribute__((address_space(3))) unsigned int*)(l), 16, 0, 0);
}

// ---------------------------------------------------------------------------
// GEMM1 (m97 structure, PASS-verified round 3) + fused alpha-pool partials.
// 128x128 tile, BK=32, 4 waves; wave (wr,wc) owns 64x64; acc 4x4 16x16 frags.
// C/D map: row = wr*64+i*16+(lane>>4)*4+p, col = wc*64+j*16+(lane&15).
// For q-blocks (d0<512): wave's cols = one full head; fused flash partials
// (m,s,pv[64]) per (bh, chunk), chunk = mchunk*8 + wr*4 + g (256 per bh).
// ---------------------------------------------------------------------------
__global__ __launch_bounds__(256, 2)
void k_gemm1(const unsigned short* __restrict__ Ag, const unsigned short* __restrict__ Bg,
             const float* __restrict__ Wq,
             float* __restrict__ outQ, unsigned short* __restrict__ outK,
             unsigned short* __restrict__ outV,
             float* __restrict__ pm1, float* __restrict__ ps1, float* __restrict__ pv1)
{
    __shared__ __align__(16) unsigned char lds[16384];   // A 8KB | B 8KB
    const int m0 = blockIdx.x * 128;
    const int d0 = blockIdx.y * 128;
    const int t = threadIdx.x, lane = t & 63, w = t >> 6;
    const int wr = w >> 1, wc = w & 1;
    const int lrow = lane >> 2, lslot = lane & 3;
    const int fr = lane & 15, g = lane >> 4;

    f32x4 acc[4][4];
    #pragma unroll
    for (int i = 0; i < 4; ++i)
        #pragma unroll
        for (int j = 0; j < 4; ++j) acc[i][j] = (f32x4){0.f,0.f,0.f,0.f};

    for (int k0 = 0; k0 < K_; k0 += 32) {
        #pragma unroll
        for (int s = 0; s < 2; ++s) {
            const int seg = w*2 + s;
            const int row = seg*16 + lrow;
            const int ch  = lslot ^ ((row >> 1) & 3);
            gl_lds16(Ag + (size_t)(m0+row)*K_ + k0 + ch*8, lds + seg*1024);
            gl_lds16(Bg + (size_t)(d0+row)*K_ + k0 + ch*8, lds + 8192 + seg*1024);
        }
        __syncthreads();
        bf16x8 aF[4], bF[4];
        #pragma unroll
        for (int i = 0; i < 4; ++i) {
            const int r = wr*64 + i*16 + fr;
            const int sl = g ^ ((r >> 1) & 3);
            aF[i] = *(const bf16x8*)(lds + r*64 + sl*16);
        }
        #pragma unroll
        for (int j = 0; j < 4; ++j) {
            const int r = wc*64 + j*16 + fr;
            const int sl = g ^ ((r >> 1) & 3);
            bF[j] = *(const bf16x8*)(lds + 8192 + r*64 + sl*16);
        }
        #pragma unroll
        for (int i = 0; i < 4; ++i)
            #pragma unroll
            for (int j = 0; j < 4; ++j)
                acc[i][j] = __builtin_amdgcn_mfma_f32_16x16x32_bf16(aF[i], bF[j], acc[i][j], 0, 0, 0);
        __syncthreads();
    }

    // ---- output writes ----
    #pragma unroll
    for (int i = 0; i < 4; ++i)
        #pragma unroll
        for (int j = 0; j < 4; ++j) {
            const int trow = wr*64 + i*16 + g*4;
            const int tcol = wc*64 + j*16 + fr;
            const int d = d0 + tcol;
            #pragma unroll
            for (int p = 0; p < 4; ++p) {
                const size_t m = (size_t)(m0 + trow + p);
                const float vv = acc[i][j][p];
                if (d0 < C_)          outQ[m*C_ + d] = vv;
                else if (d0 < 2*C_)   outK[m*C_ + (d - C_)] = f2bf(vv);
                else                  outV[m*C_ + (d - 2*C_)] = f2bf(vv);
            }
        }

    // ---- fused alpha-pool partials (q-blocks only) ----
    if (d0 < C_) {
        const int head = (d0 >> 6) + wc;            // wave's head
        const int b = m0 >> 12;
        const int bh = b*8 + head;
        const int mchunk = (m0 & 4095) >> 7;        // 0..31
        const int chunk = mchunk*8 + wr*4 + g;      // 0..255
        float wqv[4];
        #pragma unroll
        for (int j = 0; j < 4; ++j) wqv[j] = Wq[head*HD_ + j*16 + fr] * SCALE_;

        float s[4][4];
        #pragma unroll
        for (int i = 0; i < 4; ++i)
            #pragma unroll
            for (int p = 0; p < 4; ++p) {
                float d = acc[i][0][p]*wqv[0] + acc[i][1][p]*wqv[1]
                        + acc[i][2][p]*wqv[2] + acc[i][3][p]*wqv[3];
                d += __shfl_xor(d, 1); d += __shfl_xor(d, 2);
                d += __shfl_xor(d, 4); d += __shfl_xor(d, 8);
                s[i][p] = d;                        // full dot for row (i,g,p)
            }
        float mx = s[0][0];
        #pragma unroll
        for (int i = 0; i < 4; ++i)
            #pragma unroll
            for (int p = 0; p < 4; ++p) mx = fmaxf(mx, s[i][p]);
        float e[4][4]; float ssum = 0.f;
        #pragma unroll
        for (int i = 0; i < 4; ++i)
            #pragma unroll
            for (int p = 0; p < 4; ++p) { e[i][p] = __expf(s[i][p] - mx); ssum += e[i][p]; }
        #pragma unroll
        for (int j = 0; j < 4; ++j) {
            float pvj = 0.f;
            #pragma unroll
            for (int i = 0; i < 4; ++i)
                #pragma unroll
                for (int p = 0; p < 4; ++p) pvj = fmaf(e[i][p], acc[i][j][p], pvj);
            pv1[((size_t)bh*256 + chunk)*64 + j*16 + fr] = pvj;
        }
        if (fr == 0) { pm1[bh*256 + chunk] = mx; ps1[bh*256 + chunk] = ssum; }
    }
}

// combine 256 alpha partials -> global_q [64][64]
__global__ __launch_bounds__(256)
void k_comb1(const float* __restrict__ pm, const float* __restrict__ ps,
             const float* __restrict__ pv, float* __restrict__ gq)
{
    __shared__ float red[4];
    __shared__ float sred[4];
    __shared__ float pvs[4][64];
    __shared__ float stat[2];
    const int bh = blockIdx.x;
    const int t = threadIdx.x, lane = t & 63, wv = t >> 6;

    float m = pm[bh*256 + t];
    #pragma unroll
    for (int off = 32; off; off >>= 1) m = fmaxf(m, __shfl_xor(m, off));
    if (lane == 0) red[wv] = m;
    __syncthreads();
    if (t == 0) stat[0] = fmaxf(fmaxf(red[0],red[1]), fmaxf(red[2],red[3]));
    __syncthreads();
    m = stat[0];

    float e  = __expf(pm[bh*256 + t] - m);
    float sp = ps[bh*256 + t] * e;
    #pragma unroll
    for (int off = 32; off; off >>= 1) sp += __shfl_xor(sp, off);
    if (lane == 0) sred[wv] = sp;
    __syncthreads();
    if (t == 0) stat[1] = sred[0]+sred[1]+sred[2]+sred[3];

    float acc = 0.f;
    for (int c0 = 0; c0 < 64; ++c0) {
        const int ch = wv*64 + c0;
        const float ec = __expf(pm[bh*256 + ch] - m);
        acc = fmaf(pv[((size_t)bh*256 + ch)*64 + lane], ec, acc);
    }
    pvs[wv][lane] = acc;
    __syncthreads();
    if (t < 64) gq[bh*64 + t] = (pvs[0][t]+pvs[1][t]+pvs[2][t]+pvs[3][t]) / stat[1];
}

// beta pool: single-pass online over k (bf16). 1024 blocks = (bh, 16 chunks).
__global__ __launch_bounds__(256)
void k_pool2(const unsigned short* __restrict__ kb, const float* __restrict__ w_k,
             const float* __restrict__ gq,
             float* __restrict__ pm2, float* __restrict__ ps2, float* __restrict__ pv2)
{
    __shared__ float mred[4];
    __shared__ float sl[4][64];
    __shared__ float sred2[4];
    const int bid = blockIdx.x;
    const int bh = bid >> 4, ch = bid & 15;
    const int b = bh >> 3, h = bh & 7;
    const int t = threadIdx.x, lane = t & 63, wv = t >> 6;
    const float wk = w_k[h*64 + lane] * gq[bh*64 + lane] * SCALE_;
    const unsigned short* base = kb + ((size_t)b*N_ + ch*256)*C_ + h*64 + lane;

    float mw = -1e30f, sw = 0.f, pvw = 0.f;
    for (int n0 = wv*4; n0 < 256; n0 += 16) {
        float x0 = bf2f(base[(size_t)(n0+0)*C_]);
        float x1 = bf2f(base[(size_t)(n0+1)*C_]);
        float x2 = bf2f(base[(size_t)(n0+2)*C_]);
        float x3 = bf2f(base[(size_t)(n0+3)*C_]);
        float s0 = x0*wk, s1 = x1*wk, s2 = x2*wk, s3 = x3*wk;
        #pragma unroll
        for (int off = 32; off; off >>= 1) {
            s0 += __shfl_xor(s0, off); s1 += __shfl_xor(s1, off);
            s2 += __shfl_xor(s2, off); s3 += __shfl_xor(s3, off);
        }
        const float mx = fmaxf(fmaxf(s0,s1), fmaxf(s2,s3));
        const float mn = fmaxf(mw, mx);
        const float f  = __expf(mw - mn);
        const float e0 = __expf(s0 - mn), e1 = __expf(s1 - mn);
        const float e2 = __expf(s2 - mn), e3 = __expf(s3 - mn);
        sw  = sw*f  + (e0+e1+e2+e3);
        pvw = pvw*f + e0*x0 + e1*x1 + e2*x2 + e3*x3;
        mw = mn;
    }
    if (lane == 0) mred[wv] = mw;
    __syncthreads();
    const float mb = fmaxf(fmaxf(mred[0],mred[1]), fmaxf(mred[2],mred[3]));
    const float f = __expf(mw - mb);
    sl[wv][lane] = pvw * f;
    if (lane == 0) sred2[wv] = sw * f;
    __syncthreads();
    if (t < 64) {
        pv2[(size_t)bid*64 + t] = sl[0][t]+sl[1][t]+sl[2][t]+sl[3][t];
        if (t == 0) ps2[bid] = sred2[0]+sred2[1]+sred2[2]+sred2[3];
        if (t == 1) pm2[bid] = mb;
    }
}

// fold: wpb[b][d][k] = bf16(w_proj[d][k] * gkf[b][k]); gkf combined inline
// from beta partials (16 chunks).
__global__ __launch_bounds__(256)
void k_fold(const float* __restrict__ wp, const float* __restrict__ pm2,
            const float* __restrict__ ps2, const float* __restrict__ pv2,
            unsigned short* __restrict__ wpb)
{
    const int i = blockIdx.x*256 + threadIdx.x;   // quad over [8][512][512]
    const int idx4 = i*4;
    const int b  = idx4 >> 18;
    const int wi = idx4 & 262143;
    const int k  = idx4 & 511;
    const int h  = k >> 6, hd = k & 63;
    const int bh = b*8 + h;

    float m = pm2[bh*16];
    #pragma unroll
    for (int c = 1; c < 16; ++c) m = fmaxf(m, pm2[bh*16 + c]);
    float s = 0.f, g0 = 0.f, g1 = 0.f, g2 = 0.f, g3 = 0.f;
    #pragma unroll
    for (int c = 0; c < 16; ++c) {
        const float e = __expf(pm2[bh*16 + c] - m);
        s = fmaf(ps2[bh*16 + c], e, s);
        const float4 pvv = *(const float4*)(pv2 + (size_t)(bh*16 + c)*64 + hd);
        g0 = fmaf(pvv.x, e, g0); g1 = fmaf(pvv.y, e, g1);
        g2 = fmaf(pvv.z, e, g2); g3 = fmaf(pvv.w, e, g3);
    }
    const float inv = 1.0f / s;
    const float4 wv4 = *(const float4*)(wp + wi);
    ushort4 r;
    r.x = f2bf(wv4.x * g0 * inv); r.y = f2bf(wv4.y * g1 * inv);
    r.z = f2bf(wv4.z * g2 * inv); r.w = f2bf(wv4.w * g3 * inv);
    ((ushort4*)wpb)[i] = r;
}

// GEMM2 (unchanged, PASS-verified): out = v@wpb^T + bproj + q(in place)
__global__ __launch_bounds__(256, 2)
void k_gemm2(const unsigned short* __restrict__ Ag, const unsigned short* __restrict__ Wpb,
             const float* __restrict__ bproj, float* __restrict__ out)
{
    __shared__ __align__(16) unsigned char lds[16384];
    const int m0 = blockIdx.x * 128;
    const int d0 = blockIdx.y * 128;
    const int b  = m0 >> 12;
    const unsigned short* Bg = Wpb + (size_t)b * C_ * C_;
    const int t = threadIdx.x, lane = t & 63, w = t >> 6;
    const int wr = w >> 1, wc = w & 1;
    const int lrow = lane >> 2, lslot = lane & 3;
    const int fr = lane & 15, g = lane >> 4;

    f32x4 acc[4][4];
    #pragma unroll
    for (int i = 0; i < 4; ++i)
        #pragma unroll
        for (int j = 0; j < 4; ++j) acc[i][j] = (f32x4){0.f,0.f,0.f,0.f};

    for (int k0 = 0; k0 < K_; k0 += 32) {
        #pragma unroll
        for (int s = 0; s < 2; ++s) {
            const int seg = w*2 + s;
            const int row = seg*16 + lrow;
            const int ch  = lslot ^ ((row >> 1) & 3);
            gl_lds16(Ag + (size_t)(m0+row)*K_ + k0 + ch*8, lds + seg*1024);
            gl_lds16(Bg + (size_t)(d0+row)*K_ + k0 + ch*8, lds + 8192 + seg*1024);
        }
        __syncthreads();
        bf16x8 aF[4], bF[4];
        #pragma unroll
        for (int i = 0; i < 4; ++i) {
            const int r = wr*64 + i*16 + fr;
            const int sl = g ^ ((r >> 1) & 3);
            aF[i] = *(const bf16x8*)(lds + r*64 + sl*16);
        }
        #pragma unroll
        for (int j = 0; j < 4; ++j) {
            const int r = wc*64 + j*16 + fr;
            const int sl = g ^ ((r >> 1) & 3);
            bF[j] = *(const bf16x8*)(lds + 8192 + r*64 + sl*16);
        }
        #pragma unroll
        for (int i = 0; i < 4; ++i)
            #pragma unroll
            for (int j = 0; j < 4; ++j)
                acc[i][j] = __builtin_amdgcn_mfma_f32_16x16x32_bf16(aF[i], bF[j], acc[i][j], 0, 0, 0);
        __syncthreads();
    }

    #pragma unroll
    for (int i = 0; i < 4; ++i)
        #pragma unroll
        for (int j = 0; j < 4; ++j) {
            const int trow = wr*64 + i*16 + g*4;
            const int tcol = wc*64 + j*16 + fr;
            const int d = d0 + tcol;
            const float bp = bproj[d];
            #pragma unroll
            for (int p = 0; p < 4; ++p) {
                const size_t off = (size_t)(m0 + trow + p)*C_ + d;
                out[off] = acc[i][j][p] + bp + out[off];
            }
        }
}

// merged fp32->bf16 convert for x and w_qkv
__global__ void k_cvt2(const float* __restrict__ a, const float* __restrict__ bsrc,
                       unsigned short* __restrict__ oa, unsigned short* __restrict__ ob,
                       int na4, int nb4)
{
    int i = blockIdx.x*256 + threadIdx.x;
    const int stride = gridDim.x*256;
    const int tot = na4 + nb4;
    for (; i < tot; i += stride) {
        if (i < na4) {
            const float4 f = ((const float4*)a)[i];
            ushort4 r; r.x = f2bf(f.x); r.y = f2bf(f.y); r.z = f2bf(f.z); r.w = f2bf(f.w);
            ((ushort4*)oa)[i] = r;
        } else {
            const int j = i - na4;
            const float4 f = ((const float4*)bsrc)[j];
            ushort4 r; r.x = f2bf(f.x); r.y = f2bf(f.y); r.z = f2bf(f.z); r.w = f2bf(f.w);
            ((ushort4*)ob)[j] = r;
        }
    }
}

extern "C" void kernel_launch(void* const* d_in, const int* in_sizes, int n_in,
                              void* d_out, int out_size, void* d_ws, size_t ws_size,
                              hipStream_t stream)
{
    (void)in_sizes; (void)n_in; (void)out_size; (void)ws_size;
    const float* x      = (const float*)d_in[0];
    const float* w_qkv  = (const float*)d_in[1];
    const float* w_proj = (const float*)d_in[2];
    const float* b_proj = (const float*)d_in[3];
    const float* w_q    = (const float*)d_in[4];
    const float* w_k    = (const float*)d_in[5];
    float* out = (float*)d_out;

    unsigned short* xb  = (unsigned short*)d_ws;          // [M,K]  33.5MB
    unsigned short* wqb = xb  + (size_t)M_*K_;            // [D3,K] 1.6MB
    unsigned short* kb  = wqb + (size_t)D3_*K_;           // [M,C]  33.5MB
    unsigned short* vb  = kb  + (size_t)M_*C_;            // [M,C]  33.5MB
    unsigned short* wpb = vb  + (size_t)M_*C_;            // [8,C,C] 4MB
    float* gq  = (float*)(wpb + (size_t)8*C_*C_);         // [64,64]
    float* pm1 = gq  + 64*64;                             // [64,256]
    float* ps1 = pm1 + 64*256;
    float* pv1 = ps1 + 64*256;                            // [64,256,64] 4MB
    float* pm2 = pv1 + (size_t)64*256*64;                 // [1024]
    float* ps2 = pm2 + 1024;
    float* pv2 = ps2 + 1024;                              // [1024,64]

    k_cvt2<<<2048, 256, 0, stream>>>(x, w_qkv, xb, wqb, M_*K_/4, D3_*K_/4);

    dim3 g1(M_/128, D3_/128);
    k_gemm1<<<g1, 256, 0, stream>>>(xb, wqb, w_q, out, kb, vb, pm1, ps1, pv1);

    k_comb1<<<64, 256, 0, stream>>>(pm1, ps1, pv1, gq);
    k_pool2<<<1024, 256, 0, stream>>>(kb, w_k, gq, pm2, ps2, pv2);
    k_fold<<<2048, 256, 0, stream>>>(w_proj, pm2, ps2, pv2, wpb);

    dim3 g2(M_/128, C_/128);
    k_gemm2<<<g2, 256, 0, stream>>>(vb, wpb, b_proj, out);
}